// Round 1
// 816.687 us; speedup vs baseline: 1.0262x; 1.0262x over previous
//
#include <hip/hip_runtime.h>
#include <hip/hip_bf16.h>

#define cN0 500000
#define cN1 100000
#define cN2 25000
#define cE0 1600000
#define cE1 400000

typedef __bf16 bf16x8 __attribute__((ext_vector_type(8)));
typedef __bf16 bf16x4 __attribute__((ext_vector_type(4)));
typedef float f32x4 __attribute__((ext_vector_type(4)));

// ---------------- CSR build ----------------

__global__ void k_hist(const int* __restrict__ dst, int E, int* __restrict__ cnt) {
    int i = blockIdx.x * blockDim.x + threadIdx.x;
    if (i < E) atomicAdd(&cnt[dst[i]], 1);
}

__global__ void k_scan1(int* __restrict__ a, int n, int* __restrict__ bsum) {
    __shared__ int lds[256];
    const int t = threadIdx.x;
    const int base = blockIdx.x * 1024 + t * 4;
    int v0 = (base + 0 < n) ? a[base + 0] : 0;
    int v1 = (base + 1 < n) ? a[base + 1] : 0;
    int v2 = (base + 2 < n) ? a[base + 2] : 0;
    int v3 = (base + 3 < n) ? a[base + 3] : 0;
    const int s = v0 + v1 + v2 + v3;
    lds[t] = s;
    __syncthreads();
    int x = s;
    for (int d = 1; d < 256; d <<= 1) {
        int y = (t >= d) ? lds[t - d] : 0;
        __syncthreads();
        x += y;
        lds[t] = x;
        __syncthreads();
    }
    if (t == 255) bsum[blockIdx.x] = x;
    int e0 = x - s;
    int e1 = e0 + v0, e2 = e1 + v1, e3 = e2 + v2;
    if (base + 0 < n) a[base + 0] = e0;
    if (base + 1 < n) a[base + 1] = e1;
    if (base + 2 < n) a[base + 2] = e2;
    if (base + 3 < n) a[base + 3] = e3;
}

__global__ void k_scan2(int* __restrict__ bsum, int nb) {
    __shared__ int lds[128];
    const int t = threadIdx.x;
    int v = (t < nb) ? bsum[t] : 0;
    lds[t] = v;
    __syncthreads();
    int x = v;
    for (int d = 1; d < 128; d <<= 1) {
        int y = (t >= d) ? lds[t - d] : 0;
        __syncthreads();
        x += y;
        lds[t] = x;
        __syncthreads();
    }
    if (t < nb) bsum[t] = x - v;
}

// fused: finalize row offsets AND seed the scatter cursors (was scan3 + copy)
__global__ void k_scan3(int* __restrict__ a, int n, const int* __restrict__ bsum, int total,
                        int* __restrict__ cur) {
    int i = blockIdx.x * blockDim.x + threadIdx.x;
    if (i < n) {
        int v = a[i] + bsum[i >> 10];
        a[i] = v;
        cur[i] = v;
    }
    if (i == 0) a[n] = total;
}

__global__ void k_scatter(const int* __restrict__ esrc, const int* __restrict__ edst, int E,
                          int* __restrict__ cur, int* __restrict__ srcs) {
    int i = blockIdx.x * blockDim.x + threadIdx.x;
    if (i < E) {
        int p = atomicAdd(&cur[edst[i]], 1);
        srcs[p] = esrc[i];
    }
}

// ---------------- weight concat (fp32 -> bf16) ----------------
__global__ void k_wcat0(const float* __restrict__ Wl, const float* __restrict__ Wr,
                        __bf16* __restrict__ Wc) {
    int i = blockIdx.x * blockDim.x + threadIdx.x;   // 256*256
    if (i < 256 * 256) {
        int j = i >> 8, k = i & 255;
        float v = (k < 128) ? Wl[j * 128 + k] : Wr[j * 128 + (k - 128)];
        Wc[i] = (__bf16)v;
    }
}
__global__ void k_wcat1(const float* __restrict__ Wl, const float* __restrict__ Wr,
                        __bf16* __restrict__ Wc) {
    int i = blockIdx.x * blockDim.x + threadIdx.x;   // 128*512
    if (i < 128 * 512) {
        int j = i >> 9, k = i & 511;
        float v = (k < 256) ? Wl[j * 256 + k] : Wr[j * 256 + (k - 256)];
        Wc[i] = (__bf16)v;
    }
}

// ---------------- x (fp32) -> xb (bf16) cast; also fills M0 right half ----------------
// 500000*128 = 64M elements, 8 per thread, exactly 31250 blocks x 256.
// NT loads on x keep the 256MB fp32 stream from evicting xb (128MB) out of L3.
__global__ __launch_bounds__(256) void k_cast(const float* __restrict__ x,
                                              __bf16* __restrict__ xb,
                                              __bf16* __restrict__ M0) {
    const size_t t = (size_t)blockIdx.x * 256 + threadIdx.x;
    const size_t base = t * 8;                     // element index < 64M
    const f32x4 a = __builtin_nontemporal_load((const f32x4*)(x + base));
    const f32x4 b = __builtin_nontemporal_load((const f32x4*)(x + base + 4));
    bf16x8 o;
    o[0] = (__bf16)a[0]; o[1] = (__bf16)a[1]; o[2] = (__bf16)a[2]; o[3] = (__bf16)a[3];
    o[4] = (__bf16)b[0]; o[5] = (__bf16)b[1]; o[6] = (__bf16)b[2]; o[7] = (__bf16)b[3];
    *(bf16x8*)(xb + base) = o;
    const int row = (int)(base >> 7);
    if (row < cN1) {
        const int col = (int)(base & 127);
        *(bf16x8*)(M0 + (size_t)row * 256 + 128 + col) = o;
    }
}

// ---------------- hop0 aggregation: M0[g][0:128] = bf16(mean xb_src) ----------------
// half-wave (32 lanes) per node, lane = 4 bf16 dims (8B loads, 256B/row coalesced)
__global__ __launch_bounds__(256) void k_agg0(
    const __bf16* __restrict__ xb,
    const int* __restrict__ off, const int* __restrict__ srcs,
    __bf16* __restrict__ M0)
{
    const int tid = threadIdx.x;
    const int slot = tid >> 5;          // 0..7
    const int ln = tid & 31;            // dims ln*4 .. ln*4+3
    const int g = blockIdx.x * 8 + slot;
    if (g >= cN1) return;
    const int e0 = off[g], e1 = off[g + 1];
    float a0 = 0.f, a1 = 0.f, a2 = 0.f, a3 = 0.f;
    int e = e0;
    for (; e + 4 <= e1; e += 4) {
        const int s0 = srcs[e], s1 = srcs[e + 1], s2 = srcs[e + 2], s3 = srcs[e + 3];
        const bf16x4 r0 = *(const bf16x4*)(xb + (size_t)s0 * 128 + ln * 4);
        const bf16x4 r1 = *(const bf16x4*)(xb + (size_t)s1 * 128 + ln * 4);
        const bf16x4 r2 = *(const bf16x4*)(xb + (size_t)s2 * 128 + ln * 4);
        const bf16x4 r3 = *(const bf16x4*)(xb + (size_t)s3 * 128 + ln * 4);
        a0 += ((float)r0[0] + (float)r1[0]) + ((float)r2[0] + (float)r3[0]);
        a1 += ((float)r0[1] + (float)r1[1]) + ((float)r2[1] + (float)r3[1]);
        a2 += ((float)r0[2] + (float)r1[2]) + ((float)r2[2] + (float)r3[2]);
        a3 += ((float)r0[3] + (float)r1[3]) + ((float)r2[3] + (float)r3[3]);
    }
    for (; e < e1; ++e) {
        const int s = srcs[e];
        const bf16x4 r = *(const bf16x4*)(xb + (size_t)s * 128 + ln * 4);
        a0 += (float)r[0]; a1 += (float)r[1]; a2 += (float)r[2]; a3 += (float)r[3];
    }
    const int cnt = e1 - e0;
    const float inv = 1.f / (float)(cnt > 0 ? cnt : 1);
    bf16x4 oa;
    oa[0] = (__bf16)(a0 * inv); oa[1] = (__bf16)(a1 * inv);
    oa[2] = (__bf16)(a2 * inv); oa[3] = (__bf16)(a3 * inv);
    *(bf16x4*)(M0 + (size_t)g * 256 + ln * 4) = oa;
}

// ---------------- hop1 aggregation: M1[g] = [bf16(mean h_src) | h[g]] ----------------
__global__ __launch_bounds__(256) void k_agg1(
    const __bf16* __restrict__ h,
    const int* __restrict__ off, const int* __restrict__ srcs,
    __bf16* __restrict__ M1)
{
    const int tid = threadIdx.x;
    const int wave = tid >> 6;
    const int lane = tid & 63;          // dims lane*4 .. +3
    const int g = blockIdx.x * 4 + wave;
    if (g >= cN2) return;
    const int e0 = off[g], e1 = off[g + 1];
    float a0 = 0.f, a1 = 0.f, a2 = 0.f, a3 = 0.f;
    int e = e0;
    for (; e + 4 <= e1; e += 4) {
        const int s0 = srcs[e], s1 = srcs[e + 1], s2 = srcs[e + 2], s3 = srcs[e + 3];
        const bf16x4 r0 = *(const bf16x4*)(h + (size_t)s0 * 256 + lane * 4);
        const bf16x4 r1 = *(const bf16x4*)(h + (size_t)s1 * 256 + lane * 4);
        const bf16x4 r2 = *(const bf16x4*)(h + (size_t)s2 * 256 + lane * 4);
        const bf16x4 r3 = *(const bf16x4*)(h + (size_t)s3 * 256 + lane * 4);
        a0 += (float)r0[0] + (float)r1[0] + (float)r2[0] + (float)r3[0];
        a1 += (float)r0[1] + (float)r1[1] + (float)r2[1] + (float)r3[1];
        a2 += (float)r0[2] + (float)r1[2] + (float)r2[2] + (float)r3[2];
        a3 += (float)r0[3] + (float)r1[3] + (float)r2[3] + (float)r3[3];
    }
    for (; e < e1; ++e) {
        const int s = srcs[e];
        const bf16x4 r = *(const bf16x4*)(h + (size_t)s * 256 + lane * 4);
        a0 += (float)r[0]; a1 += (float)r[1]; a2 += (float)r[2]; a3 += (float)r[3];
    }
    const int cnt = e1 - e0;
    const float inv = 1.f / (float)(cnt > 0 ? cnt : 1);
    bf16x4 oa;
    oa[0] = (__bf16)(a0 * inv); oa[1] = (__bf16)(a1 * inv);
    oa[2] = (__bf16)(a2 * inv); oa[3] = (__bf16)(a3 * inv);
    *(bf16x4*)(M1 + (size_t)g * 512 + lane * 4) = oa;
    *(bf16x4*)(M1 + (size_t)g * 512 + 256 + lane * 4) =
        *(const bf16x4*)(h + (size_t)g * 256 + lane * 4);
}

// ---------------- bf16 MFMA GEMM: C = act(Mm[Mrows x K] @ W[N x K]^T + bias) ----------------
template<int K, int LDC, bool RELU, bool OUTBF16>
__global__ __launch_bounds__(256) void k_gemm(
    const __bf16* __restrict__ Mm, const __bf16* __restrict__ W,
    const float* __restrict__ bias,
    float* __restrict__ outf, __bf16* __restrict__ outb, int Mrows)
{
    const int tid = threadIdx.x;
    const int l = tid & 63;
    const int w = tid >> 6;
    const int wm = w & 1, wn = w >> 1;
    const int row0 = blockIdx.x * 128 + wm * 64;
    const int col0 = blockIdx.y * 128 + wn * 64;
    const int lr = l & 15;          // row (A) / col (B) within fragment
    const int lk = (l >> 4) * 8;    // k offset within fragment

    const __bf16* pa[4];
    const __bf16* pb[4];
    #pragma unroll
    for (int i = 0; i < 4; ++i) {
        int r = row0 + i * 16 + lr;
        r = (r < Mrows) ? r : (Mrows - 1);
        pa[i] = Mm + (size_t)r * K + lk;
        pb[i] = W + (size_t)(col0 + i * 16 + lr) * K + lk;
    }
    f32x4 acc[4][4];
    #pragma unroll
    for (int i = 0; i < 4; ++i)
        #pragma unroll
        for (int j = 0; j < 4; ++j)
            acc[i][j] = (f32x4)0.0f;

    #pragma unroll 2
    for (int k0 = 0; k0 < K; k0 += 32) {
        bf16x8 fa[4], fb[4];
        #pragma unroll
        for (int i = 0; i < 4; ++i) fa[i] = *(const bf16x8*)(pa[i] + k0);
        #pragma unroll
        for (int j = 0; j < 4; ++j) fb[j] = *(const bf16x8*)(pb[j] + k0);
        #pragma unroll
        for (int i = 0; i < 4; ++i)
            #pragma unroll
            for (int j = 0; j < 4; ++j)
                acc[i][j] = __builtin_amdgcn_mfma_f32_16x16x32_bf16(fa[i], fb[j], acc[i][j], 0, 0, 0);
    }

    // C/D layout: col = lane&15, row = (lane>>4)*4 + reg  [m89/m91-verified]
    #pragma unroll
    for (int j = 0; j < 4; ++j) {
        const int colg = col0 + j * 16 + lr;
        const float bj = bias[colg];
        #pragma unroll
        for (int i = 0; i < 4; ++i) {
            #pragma unroll
            for (int reg = 0; reg < 4; ++reg) {
                const int rowg = row0 + i * 16 + (l >> 4) * 4 + reg;
                if (rowg < Mrows) {
                    float v = acc[i][j][reg] + bj;
                    if (RELU) v = fmaxf(v, 0.f);
                    if (OUTBF16) outb[(size_t)rowg * LDC + colg] = (__bf16)v;
                    else         outf[(size_t)rowg * LDC + colg] = v;
                }
            }
        }
    }
}

// ---------------- launch ----------------

extern "C" void kernel_launch(void* const* d_in, const int* in_sizes, int n_in,
                              void* d_out, int out_size, void* d_ws, size_t ws_size,
                              hipStream_t stream) {
    const float* x   = (const float*)d_in[0];
    const float* Wl0 = (const float*)d_in[1];
    const float* bl0 = (const float*)d_in[2];
    const float* Wr0 = (const float*)d_in[3];
    const float* Wl1 = (const float*)d_in[4];
    const float* bl1 = (const float*)d_in[5];
    const float* Wr1 = (const float*)d_in[6];
    const int* e0s = (const int*)d_in[7];
    const int* e0d = (const int*)d_in[8];
    const int* e1s = (const int*)d_in[9];
    const int* e1d = (const int*)d_in[10];
    float* out = (float*)d_out;

    char* ws = (char*)d_ws;
    size_t pos = 0;
    auto alloc = [&](size_t nb) -> void* {
        void* p = ws + pos;
        pos += (nb + 255) & ~(size_t)255;
        return p;
    };
    // xb [500K x 128] bf16 (128MB); h [100K x 256] bf16 aliases xb (xb dead after agg0)
    __bf16* xb   = (__bf16*)alloc((size_t)cN0 * 128 * 2);
    __bf16* h    = xb;
    // M0 [100K x 256] bf16 (51.2MB); M1 [25K x 512] bf16 aliases M0 (M0 dead after gemm0)
    __bf16* M0   = (__bf16*)alloc((size_t)cN1 * 256 * 2);
    __bf16* M1   = M0;
    int* off0    = (int*)alloc((size_t)(cN1 + 1) * 4);
    int* cur0    = (int*)alloc((size_t)cN1 * 4);
    int* srcs0   = (int*)alloc((size_t)cE0 * 4);
    int* off1    = (int*)alloc((size_t)(cN2 + 1) * 4);
    int* cur1    = (int*)alloc((size_t)cN2 * 4);
    int* srcs1   = (int*)alloc((size_t)cE1 * 4);
    int* bsum    = (int*)alloc(128 * 4);
    __bf16* Wc0  = (__bf16*)alloc(256 * 256 * 2);
    __bf16* Wc1  = (__bf16*)alloc(128 * 512 * 2);
    (void)ws_size; (void)in_sizes; (void)n_in; (void)out_size;

    // --- CSR build ---
    hipMemsetAsync(off0, 0, (size_t)(cN1 + 1) * 4, stream);
    hipMemsetAsync(off1, 0, (size_t)(cN2 + 1) * 4, stream);
    k_hist<<<(cE0 + 255) / 256, 256, 0, stream>>>(e0d, cE0, off0);
    k_hist<<<(cE1 + 255) / 256, 256, 0, stream>>>(e1d, cE1, off1);

    const int nb0 = (cN1 + 1023) / 1024;
    k_scan1<<<nb0, 256, 0, stream>>>(off0, cN1, bsum);
    k_scan2<<<1, 128, 0, stream>>>(bsum, nb0);
    k_scan3<<<(cN1 + 255) / 256, 256, 0, stream>>>(off0, cN1, bsum, cE0, cur0);
    k_scatter<<<(cE0 + 255) / 256, 256, 0, stream>>>(e0s, e0d, cE0, cur0, srcs0);

    const int nb1 = (cN2 + 1023) / 1024;
    k_scan1<<<nb1, 256, 0, stream>>>(off1, cN2, bsum);
    k_scan2<<<1, 128, 0, stream>>>(bsum, nb1);
    k_scan3<<<(cN2 + 255) / 256, 256, 0, stream>>>(off1, cN2, bsum, cE1, cur1);
    k_scatter<<<(cE1 + 255) / 256, 256, 0, stream>>>(e1s, e1d, cE1, cur1, srcs1);

    // --- weights to bf16 concat ---
    k_wcat0<<<(256 * 256 + 255) / 256, 256, 0, stream>>>(Wl0, Wr0, Wc0);
    k_wcat1<<<(128 * 512 + 255) / 256, 256, 0, stream>>>(Wl1, Wr1, Wc1);

    // --- x -> bf16 (also fills M0 right half); placed just before agg0 for L3 residency ---
    k_cast<<<(cN0 * 128 / 8) / 256, 256, 0, stream>>>(x, xb, M0);

    // --- hop 0 ---
    k_agg0<<<(cN1 + 7) / 8, 256, 0, stream>>>(xb, off0, srcs0, M0);
    {
        dim3 grid((cN1 + 127) / 128, 2);
        k_gemm<256, 256, true, true><<<grid, 256, 0, stream>>>(M0, Wc0, bl0, nullptr, h, cN1);
    }
    // --- hop 1 ---
    k_agg1<<<(cN2 + 3) / 4, 256, 0, stream>>>(h, off1, srcs1, M1);
    {
        dim3 grid((cN2 + 127) / 128, 1);
        k_gemm<512, 128, false, false><<<grid, 256, 0, stream>>>(M1, Wc1, bl1, out, nullptr, cN2);
    }
}